// Round 1
// baseline (769.167 us; speedup 1.0000x reference)
//
#include <hip/hip_runtime.h>
#include <hip/hip_bf16.h>

// DiversityMemory: out[256,65536] = inputs[256,2048] @ features[65536,2048]^T
// Memory-bound GEMM-NT. BM=256 (full M) so features stream from HBM exactly once.
// This version: double-buffered LDS + async-stage split (loads issued before the
// MFMA phase, converted+written after), ONE barrier per K-step, BN=64 so the
// accumulator is 32 VGPR (spill-free 2 blocks/CU), padded LDS rows (BKP=40)
// for conflict-free ds_read_b128, XCD swizzle, nontemporal F/C traffic.

typedef __bf16 bf16x8 __attribute__((ext_vector_type(8)));
typedef float  f32x4  __attribute__((ext_vector_type(4)));

constexpr int K = 2048, N = 65536;
constexpr int BM = 256, BN = 64, BK = 32, BKP = 40;   // BKP: pad 32->40 bf16 (80B rows, 16B-aligned)
constexpr int THREADS = 512;                          // 8 waves: 4(m) x 2(n), 64x32 per wave
constexpr int NT  = K / BK;                           // 64 K-steps
constexpr int ASZ = BM * BKP;                         // 10240 bf16
constexpr int BSZ = BN * BKP;                         //  2560 bf16
constexpr int BUF = ASZ + BSZ;                        // per-buffer elems; 2 bufs = 50 KB LDS

__device__ inline void pack4(__hip_bfloat16* dst, f32x4 v) {
    __hip_bfloat162 lo = __float22bfloat162_rn(make_float2(v.x, v.y));
    __hip_bfloat162 hi = __float22bfloat162_rn(make_float2(v.z, v.w));
    union { __hip_bfloat162 h[2]; unsigned long long u; } p;
    p.h[0] = lo; p.h[1] = hi;
    *reinterpret_cast<unsigned long long*>(dst) = p.u;   // 8-B LDS store (4 bf16)
}

__global__ __launch_bounds__(THREADS, 4)   // 4 waves/EU -> 2 blocks/CU, VGPR cap 128
void dm_gemm(const float* __restrict__ A,   // inputs   [256][2048]
             const float* __restrict__ F,   // features [65536][2048]
             float* __restrict__ C) {       // out      [256][65536]
    __shared__ __hip_bfloat16 sm[2 * BUF];  // 50 KB: [buf][A 256x40 | B 64x40]

    const int tid  = threadIdx.x;
    const int lane = tid & 63;
    const int w    = tid >> 6;        // 0..7
    const int wr   = w & 3;           // wave m-group: rows wr*64..+64
    const int wc   = w >> 2;          // wave n-group: cols wc*32..+32
    const int r15  = lane & 15;
    const int quad = lane >> 4;

    // XCD-aware swizzle: grid=1024, 1024%8==0 -> bijective chunked remap
    int bid = (int)blockIdx.x;
    bid = (bid & 7) * ((int)gridDim.x >> 3) + (bid >> 3);
    const int bn0 = bid * BN;

    // ---- staging map: thread covers (row = tid>>3 [+j*64 for A], k4 = (tid&7)*4)
    const int trow = tid >> 3;          // 0..63
    const int tk4  = (tid & 7) * 4;     // float offset within BK
    const float* Ag = A + (size_t)trow * K + tk4;
    const float* Fg = F + (size_t)(bn0 + trow) * K + tk4;
    __hip_bfloat16* const Aw = sm + trow * BKP + tk4;          // +j*64*BKP
    __hip_bfloat16* const Bw = sm + ASZ + trow * BKP + tk4;

    f32x4 acc[4][2] = {};   // [mi][ni], 32 f32/lane

    // ---- prologue: stage K-tile 0 into buffer 0
    {
        f32x4 a0 = *reinterpret_cast<const f32x4*>(Ag + 0 * 64 * K);
        f32x4 a1 = *reinterpret_cast<const f32x4*>(Ag + 1 * 64 * K);
        f32x4 a2 = *reinterpret_cast<const f32x4*>(Ag + 2 * 64 * K);
        f32x4 a3 = *reinterpret_cast<const f32x4*>(Ag + 3 * 64 * K);
        f32x4 b0 = __builtin_nontemporal_load(reinterpret_cast<const f32x4*>(Fg));
        pack4(Aw + 0 * 64 * BKP, a0);
        pack4(Aw + 1 * 64 * BKP, a1);
        pack4(Aw + 2 * 64 * BKP, a2);
        pack4(Aw + 3 * 64 * BKP, a3);
        pack4(Bw, b0);
    }
    __syncthreads();

    // ---- main loop: 63 pipelined K-steps, ONE barrier each
    for (int t = 0; t < NT - 1; ++t) {
        const int cur = t & 1;
        const int kn  = (t + 1) * BK;

        // P1: issue next-tile global loads (latency hidden under P2)
        f32x4 a0 = *reinterpret_cast<const f32x4*>(Ag + 0 * 64 * K + kn);
        f32x4 a1 = *reinterpret_cast<const f32x4*>(Ag + 1 * 64 * K + kn);
        f32x4 a2 = *reinterpret_cast<const f32x4*>(Ag + 2 * 64 * K + kn);
        f32x4 a3 = *reinterpret_cast<const f32x4*>(Ag + 3 * 64 * K + kn);
        f32x4 b0 = __builtin_nontemporal_load(
                       reinterpret_cast<const f32x4*>(Fg + kn));

        // P2: fragments + MFMA on current buffer
        const __hip_bfloat16* Ar = sm + cur * BUF;
        const __hip_bfloat16* Br = Ar + ASZ;
        bf16x8 af[4], bq[2];
        #pragma unroll
        for (int mi = 0; mi < 4; ++mi)
            af[mi] = *reinterpret_cast<const bf16x8*>(
                Ar + (wr * 64 + mi * 16 + r15) * BKP + quad * 8);
        #pragma unroll
        for (int ni = 0; ni < 2; ++ni)
            bq[ni] = *reinterpret_cast<const bf16x8*>(
                Br + (wc * 32 + ni * 16 + r15) * BKP + quad * 8);
        #pragma unroll
        for (int mi = 0; mi < 4; ++mi)
            #pragma unroll
            for (int ni = 0; ni < 2; ++ni)
                acc[mi][ni] = __builtin_amdgcn_mfma_f32_16x16x32_bf16(
                    af[mi], bq[ni], acc[mi][ni], 0, 0, 0);

        // P3: convert + stage next tile into the other buffer
        // (safe with a single barrier: between barrier(t-1) and barrier(t) every
        //  wave is inside iteration t, so no wave can still be reading buf[cur^1])
        __hip_bfloat16* Awn = Aw + (cur ^ 1) * BUF;
        __hip_bfloat16* Bwn = Bw + (cur ^ 1) * BUF;
        pack4(Awn + 0 * 64 * BKP, a0);
        pack4(Awn + 1 * 64 * BKP, a1);
        pack4(Awn + 2 * 64 * BKP, a2);
        pack4(Awn + 3 * 64 * BKP, a3);
        pack4(Bwn, b0);

        __syncthreads();
    }

    // ---- final K-tile (no prefetch, no trailing barrier)
    {
        const int cur = (NT - 1) & 1;
        const __hip_bfloat16* Ar = sm + cur * BUF;
        const __hip_bfloat16* Br = Ar + ASZ;
        bf16x8 af[4], bq[2];
        #pragma unroll
        for (int mi = 0; mi < 4; ++mi)
            af[mi] = *reinterpret_cast<const bf16x8*>(
                Ar + (wr * 64 + mi * 16 + r15) * BKP + quad * 8);
        #pragma unroll
        for (int ni = 0; ni < 2; ++ni)
            bq[ni] = *reinterpret_cast<const bf16x8*>(
                Br + (wc * 32 + ni * 16 + r15) * BKP + quad * 8);
        #pragma unroll
        for (int mi = 0; mi < 4; ++mi)
            #pragma unroll
            for (int ni = 0; ni < 2; ++ni)
                acc[mi][ni] = __builtin_amdgcn_mfma_f32_16x16x32_bf16(
                    af[mi], bq[ni], acc[mi][ni], 0, 0, 0);
    }

    // ---- epilogue: C/D layout col = lane&15, row = quad*4 + e  [m89/m91]
    const int col0 = bn0 + wc * 32 + r15;
    #pragma unroll
    for (int mi = 0; mi < 4; ++mi) {
        const int row0 = wr * 64 + mi * 16 + quad * 4;
        #pragma unroll
        for (int ni = 0; ni < 2; ++ni) {
            #pragma unroll
            for (int e = 0; e < 4; ++e) {
                __builtin_nontemporal_store(
                    acc[mi][ni][e],
                    &C[(size_t)(row0 + e) * N + col0 + ni * 16]);
            }
        }
    }
}

extern "C" void kernel_launch(void* const* d_in, const int* in_sizes, int n_in,
                              void* d_out, int out_size, void* d_ws, size_t ws_size,
                              hipStream_t stream) {
    const float* inputs   = (const float*)d_in[0];
    // d_in[1] = inputs_ema (unused), d_in[2] = indexes (unused)
    const float* features = (const float*)d_in[3];
    float* out = (float*)d_out;

    dim3 grid(N / BN);       // 1024 blocks
    dim3 block(THREADS);     // 512 threads
    hipLaunchKernelGGL(dm_gemm, grid, block, 0, stream, inputs, features, out);
}